// Round 11
// baseline (14.773 us; speedup 1.0000x reference)
//
#include <hip/hip_runtime.h>
#include <math.h>

#define BN   4096
#define GX   8           // i-tiles of 512 rows (2 rows per thread)
#define GY   64          // j-tiles of 64 rows
#define TJ   64          // j-tile size
#define NB   (GX * GY)   // 512 partial slots

// ln(1e-4)
#define LOGE  (-9.210340371976184f)
#define EPSF  (1e-4f)
// sT = 2*eps*ln(eps), constant for every row
#define STC   (2.0f * EPSF * LOGE)

typedef float f32x2 __attribute__((ext_vector_type(2)));
__device__ __forceinline__ f32x2 sp(float v) { return (f32x2){v, v}; }

struct IState {
    float nS0, nS1, nS2;   // -softmax
    float aI;              // sS - sT
    float w0, w1, w2;      // T_i weights for e3
    float au0, au1, au2;   // loss_2 per-class |u|
    float c0;              // loss_0 contribution
    int   ti;
};

__device__ __forceinline__ IState make_state(const float* __restrict__ src,
                                             const int* __restrict__ tgt, int i) {
    IState st;
    float x0 = src[3*i], x1 = src[3*i+1], x2 = src[3*i+2];
    float m  = fmaxf(x0, fmaxf(x1, x2));
    float e0 = expf(x0 - m), e1 = expf(x1 - m), e2 = expf(x2 - m);
    float s  = e0 + e1 + e2;
    float inv = 1.0f / s;
    float S0 = e0 * inv, S1 = e1 * inv, S2 = e2 * inv;
    float ls = logf(s);
    float L0 = x0 - m - ls, L1 = x1 - m - ls, L2 = x2 - m - ls;
    float sumLS = L0 + L1 + L2;
    float sS = S0 * L0 + S1 * L1 + S2 * L2;
    int ti = tgt[i];
    st.ti = ti;
    st.aI = sS - STC;
    st.nS0 = -S0; st.nS1 = -S1; st.nS2 = -S2;
    st.w0 = EPSF + ((ti == 0) ? (1.0f - EPSF) : 0.0f);
    st.w1 = EPSF + ((ti == 1) ? (1.0f - EPSF) : 0.0f);
    st.w2 = EPSF + ((ti == 2) ? (1.0f - EPSF) : 0.0f);
    float base = EPSF * (2.0f * LOGE - sumLS);
    st.au0 = fabsf(base + (1.0f - EPSF) * (((ti == 0) ? 0.f : LOGE) - L0));
    st.au1 = fabsf(base + (1.0f - EPSF) * (((ti == 1) ? 0.f : LOGE) - L1));
    st.au2 = fabsf(base + (1.0f - EPSF) * (((ti == 2) ? 0.f : LOGE) - L2));
    float LSt = (ti == 0) ? L0 : ((ti == 1) ? L1 : L2);
    st.c0 = -(EPSF * sumLS + (1.0f - EPSF) * LSt);
    return st;
}

// partial[bid*4 + {0,1,2,3}] = {a1, a3, c2, c0}
__global__ __launch_bounds__(256) void k_pairs(const float* __restrict__ src,
                                               const int* __restrict__ tgt,
                                               float* __restrict__ partial) {
    __shared__ float Lxs[TJ], Lys[TJ], Lzs[TJ];   // class-segmented SoA
    __shared__ int   sc[3], off[3], rk[3];
    __shared__ float4 wred[4];
    int tid = threadIdx.x;
    int bx = blockIdx.x, by = blockIdx.y;

    if (tid < 3) { sc[tid] = 0; rk[tid] = 0; }

    // ---- this thread's TWO i-row states (registers only) ----
    int iA = bx * 512 + tid;
    int iB = iA + 256;
    IState A = make_state(src, tgt, iA);
    IState B = make_state(src, tgt, iB);
    float cSame = 2.0f * EPSF * LOGE;
    float cDiff = (1.0f + EPSF) * LOGE;
    float c0 = (by == 0) ? (A.c0 + B.c0) : 0.0f;

    __syncthreads();   // sc/rk zeroed

    // ---- stage j-tile: pass 1 count classes ----
    int tj = -1;
    float jL0 = 0.f, jL1 = 0.f, jL2 = 0.f;
    if (tid < TJ) {
        int j = by * TJ + tid;
        float x0 = src[3*j], x1 = src[3*j+1], x2 = src[3*j+2];
        float m  = fmaxf(x0, fmaxf(x1, x2));
        float e0 = expf(x0 - m), e1 = expf(x1 - m), e2 = expf(x2 - m);
        float s  = e0 + e1 + e2;
        float ls = logf(s);
        jL0 = x0 - m - ls; jL1 = x1 - m - ls; jL2 = x2 - m - ls;
        tj = tgt[j];
        atomicAdd(&sc[tj], 1);
    }
    __syncthreads();
    if (tid == 0) { off[0] = 0; off[1] = sc[0]; off[2] = sc[0] + sc[1]; }
    __syncthreads();
    // ---- pass 2: scatter into class-segmented SoA ----
    if (tid < TJ) {
        int r = atomicAdd(&rk[tj], 1);
        int pos = off[tj] + r;
        Lxs[pos] = jL0; Lys[pos] = jL1; Lzs[pos] = jL2;
    }
    __syncthreads();

    // loss_2: local j-tile counts x per-class |u| (both states)
    float c2 = (float)sc[0] * (A.au0 + B.au0)
             + (float)sc[1] * (A.au1 + B.au1)
             + (float)sc[2] * (A.au2 + B.au2);

    // ---- pair loop, per class segment; both i-states share each LDS read ----
    f32x2 nS0A = sp(A.nS0), nS1A = sp(A.nS1), nS2A = sp(A.nS2), aIA = sp(A.aI);
    f32x2 w0A = sp(A.w0), w1A = sp(A.w1), w2A = sp(A.w2);
    f32x2 nS0B = sp(B.nS0), nS1B = sp(B.nS1), nS2B = sp(B.nS2), aIB = sp(B.aI);
    f32x2 w0B = sp(B.w0), w1B = sp(B.w1), w2B = sp(B.w2);
    f32x2 acc1A = sp(0.f), acc3A = sp(0.f), acc1B = sp(0.f), acc3B = sp(0.f);
    float a1s = 0.f, a3s = 0.f;

    const float4* Lx4 = reinterpret_cast<const float4*>(Lxs);
    const float4* Ly4 = reinterpret_cast<const float4*>(Lys);
    const float4* Lz4 = reinterpret_cast<const float4*>(Lzs);

    for (int s = 0; s < 3; ++s) {
        int k   = off[s];
        int end = k + sc[s];
        float csA = (s == A.ti) ? cSame : cDiff;
        float csB = (s == B.ti) ? cSame : cDiff;
        f32x2 cvA = sp(csA), cvB = sp(csB);
        // scalar head to 4-alignment
        while (k < end && (k & 3)) {
            float lx = Lxs[k], ly = Lys[k], lz = Lzs[k];
            float gA = fmaf(A.nS0, lx, fmaf(A.nS1, ly, fmaf(A.nS2, lz, A.aI)));
            a1s += fabsf(gA + csA);
            a3s += fabsf(fmaf(A.w0, lx, fmaf(A.w1, ly, fmaf(A.w2, lz, gA))));
            float gB = fmaf(B.nS0, lx, fmaf(B.nS1, ly, fmaf(B.nS2, lz, B.aI)));
            a1s += fabsf(gB + csB);
            a3s += fabsf(fmaf(B.w0, lx, fmaf(B.w1, ly, fmaf(B.w2, lz, gB))));
            ++k;
        }
        // packed main: 4 j's per float4 group, both i-states per read
        #pragma unroll 2
        while (k + 3 < end) {
            int p = k >> 2;
            float4 qx = Lx4[p], qy = Ly4[p], qz = Lz4[p];   // broadcast reads
            f32x2 lx, ly, lz, g, t, e;
            // half 01
            lx = (f32x2){qx.x, qx.y}; ly = (f32x2){qy.x, qy.y}; lz = (f32x2){qz.x, qz.y};
            g = __builtin_elementwise_fma(nS2A, lz, aIA);
            g = __builtin_elementwise_fma(nS1A, ly, g);
            g = __builtin_elementwise_fma(nS0A, lx, g);
            t = g + cvA;
            acc1A += __builtin_elementwise_max(t, -t);
            e = __builtin_elementwise_fma(w2A, lz, g);
            e = __builtin_elementwise_fma(w1A, ly, e);
            e = __builtin_elementwise_fma(w0A, lx, e);
            acc3A += __builtin_elementwise_max(e, -e);
            g = __builtin_elementwise_fma(nS2B, lz, aIB);
            g = __builtin_elementwise_fma(nS1B, ly, g);
            g = __builtin_elementwise_fma(nS0B, lx, g);
            t = g + cvB;
            acc1B += __builtin_elementwise_max(t, -t);
            e = __builtin_elementwise_fma(w2B, lz, g);
            e = __builtin_elementwise_fma(w1B, ly, e);
            e = __builtin_elementwise_fma(w0B, lx, e);
            acc3B += __builtin_elementwise_max(e, -e);
            // half 23
            lx = (f32x2){qx.z, qx.w}; ly = (f32x2){qy.z, qy.w}; lz = (f32x2){qz.z, qz.w};
            g = __builtin_elementwise_fma(nS2A, lz, aIA);
            g = __builtin_elementwise_fma(nS1A, ly, g);
            g = __builtin_elementwise_fma(nS0A, lx, g);
            t = g + cvA;
            acc1A += __builtin_elementwise_max(t, -t);
            e = __builtin_elementwise_fma(w2A, lz, g);
            e = __builtin_elementwise_fma(w1A, ly, e);
            e = __builtin_elementwise_fma(w0A, lx, e);
            acc3A += __builtin_elementwise_max(e, -e);
            g = __builtin_elementwise_fma(nS2B, lz, aIB);
            g = __builtin_elementwise_fma(nS1B, ly, g);
            g = __builtin_elementwise_fma(nS0B, lx, g);
            t = g + cvB;
            acc1B += __builtin_elementwise_max(t, -t);
            e = __builtin_elementwise_fma(w2B, lz, g);
            e = __builtin_elementwise_fma(w1B, ly, e);
            e = __builtin_elementwise_fma(w0B, lx, e);
            acc3B += __builtin_elementwise_max(e, -e);
            k += 4;
        }
        // scalar tail
        while (k < end) {
            float lx = Lxs[k], ly = Lys[k], lz = Lzs[k];
            float gA = fmaf(A.nS0, lx, fmaf(A.nS1, ly, fmaf(A.nS2, lz, A.aI)));
            a1s += fabsf(gA + csA);
            a3s += fabsf(fmaf(A.w0, lx, fmaf(A.w1, ly, fmaf(A.w2, lz, gA))));
            float gB = fmaf(B.nS0, lx, fmaf(B.nS1, ly, fmaf(B.nS2, lz, B.aI)));
            a1s += fabsf(gB + csB);
            a3s += fabsf(fmaf(B.w0, lx, fmaf(B.w1, ly, fmaf(B.w2, lz, gB))));
            ++k;
        }
    }
    f32x2 acc1 = acc1A + acc1B, acc3 = acc3A + acc3B;
    float a1 = acc1.x + acc1.y + a1s;
    float a3 = acc3.x + acc3.y + a3s;

    // ---- block reduction via wave shuffles ----
    for (int o = 32; o > 0; o >>= 1) {
        a1 += __shfl_down(a1, o);
        a3 += __shfl_down(a3, o);
        c2 += __shfl_down(c2, o);
        c0 += __shfl_down(c0, o);
    }
    int lane = tid & 63, wid = tid >> 6;
    if (lane == 0) wred[wid] = make_float4(a1, a3, c2, c0);
    __syncthreads();
    if (tid == 0) {
        float4 p = wred[0];
        #pragma unroll
        for (int w = 1; w < 4; ++w) {
            p.x += wred[w].x; p.y += wred[w].y;
            p.z += wred[w].z; p.w += wred[w].w;
        }
        int bid = by * GX + bx;
        *reinterpret_cast<float4*>(partial + bid * 4) = p;
    }
}

// ---------------- kernel 2: reduce partials, finalize ----------------
__global__ __launch_bounds__(512) void k_final(const float* __restrict__ partial,
                                               float* __restrict__ out) {
    __shared__ double s1[512], s3[512], s2[512], s0[512];
    int tid = threadIdx.x;
    float4 p = *reinterpret_cast<const float4*>(partial + tid * 4);
    s1[tid] = (double)p.x; s3[tid] = (double)p.y;
    s2[tid] = (double)p.z; s0[tid] = (double)p.w;
    __syncthreads();
    for (int s = 256; s > 0; s >>= 1) {
        if (tid < s) {
            s1[tid] += s1[tid + s]; s3[tid] += s3[tid + s];
            s2[tid] += s2[tid + s]; s0[tid] += s0[tid + s];
        }
        __syncthreads();
    }
    if (tid == 0) {
        double n2 = (double)BN * (double)BN;
        double l0 = s0[0] / (double)BN;
        double l1 = (1e-4 + s1[0]) / n2;
        double l2 = (1e-4 + s2[0]) / n2;
        double l3 = (1e-4 + s3[0]) / n2;
        out[0] = (float)((l0 + l1) + (l2 + l3));
        out[1] = (float)l0;
        out[2] = (float)l1;
        out[3] = (float)l2;
        out[4] = (float)l3;
    }
}

extern "C" void kernel_launch(void* const* d_in, const int* in_sizes, int n_in,
                              void* d_out, int out_size, void* d_ws, size_t ws_size,
                              hipStream_t stream) {
    const float* src = (const float*)d_in[0];
    const int*   tgt = (const int*)d_in[1];
    float*       out = (float*)d_out;
    float*   partial = (float*)d_ws;    // NB*4 floats, fully rewritten every call

    k_pairs<<<dim3(GX, GY), 256, 0, stream>>>(src, tgt, partial);
    k_final<<<1, 512, 0, stream>>>(partial, out);
}